// Round 18
// baseline (188.282 us; speedup 1.0000x reference)
//
#include <hip/hip_runtime.h>
#include <hip/hip_bf16.h>
#include <stdint.h>

// LSTM cell as one fused bf16 MFMA GEMM — R15 sync skeleton + 32x32x16 MFMA:
//   gates(8192 x 4096) = A(8192 x 2048) @ Bp(4096 x 2048)^T + fused LSTM epilogue.
// A = [x | h_prev] bf16. Bp rows gate-interleaved per 16 hidden units:
//   packed row r = (h/16)*64 + g*16 + (h%16).
//
// ROUND 18: mfma_f32_16x16x32 -> mfma_f32_32x32x16. m119: 32x32 shape runs at
// 2495 TF vs 2176 TF (16x16) -> MFMA pipe floor per K-tile 2483 -> 2066 cy
// (-17%), half the MFMA instruction count. LDS traffic unchanged (24
// ds_read_b128/wave/tile, geometry-determined). Registers unchanged (acc
// 4x2xf32x16 = 128; frags 64). Sync structure = R15 verbatim (2 barriers +
// counted vmcnt(4) per K-tile).
// New per-wave geometry: M_rep=4 (4x32 rows), N_rep=2 (2x32 packed cols),
// 4 k-groups of 16 per BK=64 tile, 8 MFMA per phase (vs 16).
// Fragment layouts (32x32): A/B: row(col)=lane&31, k=(lane>>5)*8+j;
// C/D (m74/m101-verified): col=lane&31, row=(reg&3)+8*(reg>>2)+4*(lane>>5).
// Gate mapping: frag nn, lane l -> gate 2*nn + ((l>>4)&1), h=(bn*4+wn)*16+(l&15)
// -> lane pair (l, l^16) holds all 4 gates of one (row,h): exchange via
// __shfl_xor(.,16), then low half stores h_new, high half stores c_new.
// Quarter-wave conflict check: 16 lanes/quarter read 16 consecutive rows at
// one logical chunk, XOR row&7 -> 2-way = free (matches measured 0 conflicts).

#define B_DIM 8192
#define I_DIM 1024
#define H_DIM 1024
#define K_DIM 2048   // I + H
#define N_DIM 4096   // 4 gates * H
#define NKT   32     // K_DIM / 64

typedef short bf16x8 __attribute__((ext_vector_type(8)));
typedef float f32x16 __attribute__((ext_vector_type(16)));

__device__ __forceinline__ unsigned short f2bf(float f) {
  unsigned int u = __float_as_uint(f);
  u += 0x7FFFu + ((u >> 16) & 1u);   // RNE
  return (unsigned short)(u >> 16);
}

// ---- merged pack: A = [x|h] -> bf16 row-major (B_DIM,K_DIM);
//      B = 8 weight mats -> bf16 (N_DIM,K_DIM), gate-interleaved rows ----
__global__ void pack_AB_kernel(const float* __restrict__ x, const float* __restrict__ h,
                               const float* __restrict__ Wxi, const float* __restrict__ Whi,
                               const float* __restrict__ Wxf, const float* __restrict__ Whf,
                               const float* __restrict__ Wxc, const float* __restrict__ Whc,
                               const float* __restrict__ Wxo, const float* __restrict__ Who,
                               unsigned short* __restrict__ outA,
                               unsigned short* __restrict__ outB) {
  const int totalA = B_DIM * K_DIM / 8;             // 2M 16B-units
  const int total  = totalA + N_DIM * K_DIM / 8;    // +1M
  for (int idx = blockIdx.x * blockDim.x + threadIdx.x; idx < total;
       idx += gridDim.x * blockDim.x) {
    const float* src;
    unsigned short* dst;
    if (idx < totalA) {
      int row = idx >> 8;              // K_DIM/8 = 256 units/row
      int col = (idx & 255) * 8;
      src = (col < I_DIM) ? (x + (size_t)row * I_DIM + col)
                          : (h + (size_t)row * H_DIM + (col - I_DIM));
      dst = outA + (size_t)idx * 8;
    } else {
      int u2 = idx - totalA;
      int r = u2 >> 8;
      int k = (u2 & 255) * 8;
      int g = (r >> 4) & 3;
      int hh = ((r >> 6) << 4) | (r & 15);
      src = (k < I_DIM)
          ? ((g == 0 ? Wxi : g == 1 ? Wxf : g == 2 ? Wxc : Wxo) + (size_t)hh * I_DIM + k)
          : ((g == 0 ? Whi : g == 1 ? Whf : g == 2 ? Whc : Who) + (size_t)hh * H_DIM + (k - I_DIM));
      dst = outB + (size_t)u2 * 8;
    }
    const float4* s4 = (const float4*)src;
    float4 v0 = s4[0], v1 = s4[1];
    bf16x8 o;
    o[0] = f2bf(v0.x); o[1] = f2bf(v0.y); o[2] = f2bf(v0.z); o[3] = f2bf(v0.w);
    o[4] = f2bf(v1.x); o[5] = f2bf(v1.y); o[6] = f2bf(v1.z); o[7] = f2bf(v1.w);
    *(bf16x8*)dst = o;
  }
}

// ---- GEMM 256x256 tile, BK=64, 8 waves (2Mx4N), 32x32x16 MFMA ----
// LDS map (bytes): sA[buf][half] = buf*32768 + half*16384            (0..65536)
//                  sB[buf][half] = 65536 + buf*32768 + half*16384    (65536..131072)

#define STAGE(gptr, slotoff, ktile) do {                                          \
    int _ktc = (ktile) < NKT ? (ktile) : (NKT - 1);                               \
    const unsigned short* _g = (gptr) + (size_t)_ktc * 64;                        \
    __builtin_amdgcn_global_load_lds(                                             \
        (const __attribute__((address_space(1))) void*)_g,                        \
        (__attribute__((address_space(3))) void*)(lds + (slotoff) + wid * 1024),  \
        16, 0, 0);                                                                \
    __builtin_amdgcn_global_load_lds(                                             \
        (const __attribute__((address_space(1))) void*)(_g + (size_t)64 * K_DIM), \
        (__attribute__((address_space(3))) void*)(lds + (slotoff) + 8192 + wid * 1024), \
        16, 0, 0);                                                                \
  } while (0)

// phase (MH, kg-pair): 8 independent-accum MFMAs (2 m-tiles x 2 n-tiles x 2 kg)
#define MFMAP32(MH, AR, BR)                                                       \
  _Pragma("unroll") for (int mf2 = 0; mf2 < 2; ++mf2)                             \
  _Pragma("unroll") for (int nn = 0; nn < 2; ++nn)                                \
  _Pragma("unroll") for (int kg2 = 0; kg2 < 2; ++kg2)                             \
    acc[(MH)*2 + mf2][nn] = __builtin_amdgcn_mfma_f32_32x32x16_bf16(              \
        AR[mf2*2 + kg2], BR[nn*2 + kg2], acc[(MH)*2 + mf2][nn], 0, 0, 0)

// A frags: 2 m-tiles of mh MH, kg-pair KGP (4 frags)
#define RD_A32(DST, MH, KGP, BO)                                                  \
  _Pragma("unroll") for (int mf2 = 0; mf2 < 2; ++mf2)                             \
  _Pragma("unroll") for (int kg2 = 0; kg2 < 2; ++kg2)                             \
    DST[mf2*2 + kg2] = *(const bf16x8*)(ldsAr + (BO) + ((MH)*2 + mf2) * 4096 + rdk[(KGP)*2 + kg2]);

// B frags: 2 n-tiles, kg-pair KGP (4 frags)
#define RD_B32(DST, KGP, BO)                                                      \
  _Pragma("unroll") for (int nn = 0; nn < 2; ++nn)                                \
  _Pragma("unroll") for (int kg2 = 0; kg2 < 2; ++kg2)                             \
    DST[nn*2 + kg2] = *(const bf16x8*)(ldsBr + (BO) + nn * 4096 + rdk[(KGP)*2 + kg2]);

#define KTILE(BUF, KT) do {                                                       \
    const int _bo = (BUF) * 32768;                                                \
    const int _bo1 = ((BUF) ^ 1) * 32768;                                         \
    /* p0 (free-run) */                                                           \
    __builtin_amdgcn_s_setprio(1);                                                \
    MFMAP32(0, AQa, BHa);                                                         \
    __builtin_amdgcn_s_setprio(0);                                                \
    RD_A32(AQb, 1, 0, _bo);                                                       \
    /* p1 */                                                                      \
    __builtin_amdgcn_s_setprio(1);                                                \
    MFMAP32(1, AQb, BHa);                                                         \
    __builtin_amdgcn_s_setprio(0);                                                \
    RD_B32(BHb, 1, _bo);                                                          \
    RD_A32(AQa, 0, 1, _bo);                                                       \
    __builtin_amdgcn_s_barrier();   /* LOAD-BEARING: B-slots of buf[T] fully */   \
    /* p2: stage B(T+2) into buf[T]   read after this point                 */    \
    __builtin_amdgcn_s_setprio(1);                                                \
    MFMAP32(0, AQa, BHb);                                                         \
    __builtin_amdgcn_s_setprio(0);                                                \
    RD_A32(AQb, 1, 1, _bo);                                                       \
    STAGE(gB0p, 65536 + _bo, (KT) + 2);                                           \
    STAGE(gB1p, 65536 + _bo + 16384, (KT) + 2);                                   \
    asm volatile("s_waitcnt vmcnt(4)" ::: "memory");                              \
    __builtin_amdgcn_s_barrier();   /* LOAD-BEARING: makes vmcnt collective */    \
    /* p3 (free-run): cross-buffer reads of T+1 */                                \
    __builtin_amdgcn_s_setprio(1);                                                \
    MFMAP32(1, AQb, BHb);                                                         \
    __builtin_amdgcn_s_setprio(0);                                                \
    RD_A32(AQa, 0, 0, _bo1);                                                      \
    RD_B32(BHa, 0, _bo1);                                                         \
    STAGE(gA0p, _bo, (KT) + 2);                                                   \
    STAGE(gA1p, _bo + 16384, (KT) + 2);                                           \
  } while (0)

__launch_bounds__(512, 2)
__global__ void lstm_gemm_kernel(const unsigned short* __restrict__ A,
                                 const unsigned short* __restrict__ Bp,
                                 const float* __restrict__ c_prev,
                                 const float* __restrict__ bxi, const float* __restrict__ bhi,
                                 const float* __restrict__ bxf, const float* __restrict__ bhf,
                                 const float* __restrict__ bxc, const float* __restrict__ bhc,
                                 const float* __restrict__ bxo, const float* __restrict__ bho,
                                 float* __restrict__ out) {
  __shared__ __align__(16) char lds[131072];

  // XCD-aware bijective swizzle (512 % 8 == 0)
  const int nwg = gridDim.x;
  int bid = blockIdx.x;
  int q = nwg >> 3;
  int wg = (bid & 7) * q + (bid >> 3);
  int bm = wg >> 4;          // 32 M-tiles
  int bn = wg & 15;          // 16 N-tiles

  int tid = threadIdx.x;
  int lane = tid & 63;
  int wid = tid >> 6;        // 8 waves
  int wm = wid >> 2;         // 2 M-wave rows (128 rows each)
  int wn = wid & 3;          // 4 N-wave cols (64 cols each)

  // staging addresses: per half-tile, wave covers 8 rows x 128B; pre-swizzled
  // global source (rule #21): linear LDS dest, src chunk XOR row&7, same XOR on read.
  int srow = lane >> 3;                 // row within 8-row stripe
  int schunk = (lane & 7) ^ srow;       // swizzled 16B chunk
  const unsigned short* gA0p = A  + (size_t)(bm * 256 + wid * 8 + srow) * K_DIM + schunk * 8;
  const unsigned short* gA1p = gA0p + (size_t)128 * K_DIM;
  const unsigned short* gB0p = Bp + (size_t)(bn * 256 + wid * 8 + srow) * K_DIM + schunk * 8;
  const unsigned short* gB1p = gB0p + (size_t)128 * K_DIM;

  // LDS read bases (byte ptrs) for 32x32 frags: row = lane&31, k-group chunk
  // = kg*2 + (lane>>5), phys = logical ^ (row&7) = ^ (lane&7).
  int c31 = lane & 31;
  int l7 = lane & 7;
  int klane = lane >> 5;                // k-half within frag (0..1)
  const char* ldsAr = lds + wm * 16384 + c31 * 128;
  const char* ldsBr = lds + 65536 + wn * 8192 + c31 * 128;
  int rdk[4];
#pragma unroll
  for (int kg = 0; kg < 4; ++kg)
    rdk[kg] = ((kg * 2 + klane) ^ l7) << 4;

  f32x16 acc[4][2];
#pragma unroll
  for (int m = 0; m < 4; ++m)
#pragma unroll
    for (int n = 0; n < 2; ++n)
#pragma unroll
      for (int e = 0; e < 16; ++e) acc[m][n][e] = 0.f;

  bf16x8 AQa[4], AQb[4];   // A: 2 m-tiles x 2 kg (ping/pong over (mh, kg-pair))
  bf16x8 BHa[4], BHb[4];   // B: 2 n-tiles x 2 kg (ping/pong over kg-pair)

  // ---- prologue: stage tile0 -> buf0, tile1 -> buf1 (16 loads);
  // vmcnt(8) -> buf0 landed collectively after barrier; pre-read p0 operands. ----
  STAGE(gA0p, 0, 0);
  STAGE(gA1p, 16384, 0);
  STAGE(gB0p, 65536, 0);
  STAGE(gB1p, 65536 + 16384, 0);
  STAGE(gA0p, 32768, 1);
  STAGE(gA1p, 32768 + 16384, 1);
  STAGE(gB0p, 65536 + 32768, 1);
  STAGE(gB1p, 65536 + 32768 + 16384, 1);
  asm volatile("s_waitcnt vmcnt(8)" ::: "memory");
  __builtin_amdgcn_s_barrier();
  RD_A32(AQa, 0, 0, 0);
  RD_B32(BHa, 0, 0);

#pragma unroll 1
  for (int kt = 0; kt < NKT; kt += 2) {
    KTILE(0, kt);
    KTILE(1, kt + 1);
  }

  // ---- fused LSTM epilogue (32x32 C/D layout) ----
  // frag nn, lane l: packed col = bn*256 + wn*64 + nn*32 + (l&31)
  //   -> gate = 2*nn + ((l>>4)&1), h = (bn*4+wn)*16 + (l&15)
  // row = bm*256 + wm*128 + m*32 + (reg&3) + 8*(reg>>2) + 4*(lane>>5)
  // Lane pair (l, l^16) holds all 4 gates of the same (row, h): exchange via
  // __shfl_xor(.,16); low half stores h_new, high half stores c_new.
  int h = (bn * 4 + wn) * 16 + (lane & 15);
  int bit16 = lane & 16;
  float bi = bxi[h] + bhi[h];
  float bf_ = bxf[h] + bhf[h];
  float bc = bxc[h] + bhc[h];
  float bo = bxo[h] + bho[h];
  int row0 = bm * 256 + wm * 128 + 4 * (lane >> 5);
  size_t outsel = bit16 ? (size_t)B_DIM * H_DIM : 0;
#pragma unroll
  for (int m = 0; m < 4; ++m) {
#pragma unroll
    for (int reg = 0; reg < 16; ++reg) {
      int r = row0 + m * 32 + (reg & 3) + 8 * (reg >> 2);
      size_t off = (size_t)r * H_DIM + h;
      float o0 = acc[m][0][reg];            // gate i (low half) / f (high half)
      float o1 = acc[m][1][reg];            // gate c (low half) / o (high half)
      float x0 = __shfl_xor(o0, 16);
      float x1 = __shfl_xor(o1, 16);
      float zi = (bit16 ? x0 : o0) + bi;
      float zf = (bit16 ? o0 : x0) + bf_;
      float zc = (bit16 ? x1 : o1) + bc;
      float zo = (bit16 ? o1 : x1) + bo;
      float ig = 1.f / (1.f + __expf(-zi));
      float fg = 1.f / (1.f + __expf(-zf));
      float e2 = __expf(-2.f * zc);
      float gg = (1.f - e2) / (1.f + e2);       // tanh(zc)
      float og = 1.f / (1.f + __expf(-zo));
      float cp = c_prev[off];
      float cn = fg * cp + ig * gg;
      float e2c = __expf(-2.f * cn);
      float th = (1.f - e2c) / (1.f + e2c);     // tanh(cn)
      float hv = og * th;
      out[off + outsel] = bit16 ? cn : hv;      // low: h_new, high: c_new
    }
  }
}

extern "C" void kernel_launch(void* const* d_in, const int* in_sizes, int n_in,
                              void* d_out, int out_size, void* d_ws, size_t ws_size,
                              hipStream_t stream) {
  const float* x      = (const float*)d_in[0];
  const float* h_prev = (const float*)d_in[1];
  const float* c_prev = (const float*)d_in[2];
  const float* Wxi = (const float*)d_in[3];
  const float* Whi = (const float*)d_in[4];
  const float* Wxf = (const float*)d_in[5];
  const float* Whf = (const float*)d_in[6];
  const float* Wxc = (const float*)d_in[7];
  const float* Whc = (const float*)d_in[8];
  const float* Wxo = (const float*)d_in[9];
  const float* Who = (const float*)d_in[10];
  const float* bxi = (const float*)d_in[11];
  const float* bhi = (const float*)d_in[12];
  const float* bxf = (const float*)d_in[13];
  const float* bhf = (const float*)d_in[14];
  const float* bxc = (const float*)d_in[15];
  const float* bhc = (const float*)d_in[16];
  const float* bxo = (const float*)d_in[17];
  const float* bho = (const float*)d_in[18];

  unsigned short* Abf = (unsigned short*)d_ws;                                      // 32 MiB
  unsigned short* Bbf = (unsigned short*)((char*)d_ws + (size_t)B_DIM * K_DIM * 2); // +16 MiB

  pack_AB_kernel<<<2048, 256, 0, stream>>>(x, h_prev,
      Wxi, Whi, Wxf, Whf, Wxc, Whc, Wxo, Who, Abf, Bbf);
  lstm_gemm_kernel<<<512, 512, 0, stream>>>(Abf, Bbf, c_prev,
      bxi, bhi, bxf, bhf, bxc, bhc, bxo, bho, (float*)d_out);
}

// Round 19
// 150.175 us; speedup vs baseline: 1.2538x; 1.2538x over previous
//
#include <hip/hip_runtime.h>
#include <hip/hip_bf16.h>
#include <stdint.h>

// LSTM cell as one fused bf16 MFMA GEMM — FINAL (= round 15/17, session best ~150.2us):
//   gates(8192 x 4096) = A(8192 x 2048) @ Bp(4096 x 2048)^T + fused LSTM epilogue.
// A = [x | h_prev] bf16. Bp rows gate-interleaved per 16 hidden units:
//   packed row r = (h/16)*64 + g*16 + (h%16) -> wave's 4 N-frags = 4 gates of
//   the same h -> epilogue fully in-register (no gates buffer materialized).
//
// GEMM: 256x256 tile, BK=64, 8 waves (2Mx4N), 16x16x32 MFMA, MFMA-first 4
// phases/K-tile, operands read one phase ahead (ping-pong frag regs),
// global_load_lds staging with counted vmcnt(4), TWO barriers per K-tile
// (p1-end: slot-reuse fence for B(T+2)@p2; p2-end: collectivizes the per-wave
// vmcnt before cross-buffer reads). Free-run p3+p0+p1 gives cross-wave overlap.
//
// Session lessons encoded:
//  - counted-vmcnt queue purity: no plain loads between global_load_lds ops
//    (in-order queue couples completion; R9 -46%).
//  - vmcnt is PER-WAVE: cross-wave LDS visibility needs vmcnt THEN s_barrier
//    before reading sibling-staged slots (R11/R12 race).
//  - never drain vmcnt(0) in the main loop (R16: -4us vs counted vmcnt(4)).
//  - barrier removal only where a kept barrier already fences the slot's
//    last-read->overwrite window (R15: 4->2 barriers, +1.5% util).
//  - 16x16x32 over 32x32x16: the 32x32 frag read (32 consecutive rows x 1
//    chunk per half-wave) defeats the row&7 XOR swizzle -> 4-way bank
//    conflict, +25% time (R18). 16x16's 16-rows x 4-kgroup pattern is
//    conflict-free with this layout.
//  - pre-swizzled staging source + same-XOR read (rule #21); clamped-tail
//    uniform load count keeps vmcnt arithmetic exact through the last tile.

#define B_DIM 8192
#define I_DIM 1024
#define H_DIM 1024
#define K_DIM 2048   // I + H
#define N_DIM 4096   // 4 gates * H
#define NKT   32     // K_DIM / 64

typedef short bf16x8 __attribute__((ext_vector_type(8)));
typedef float f32x4 __attribute__((ext_vector_type(4)));

__device__ __forceinline__ unsigned short f2bf(float f) {
  unsigned int u = __float_as_uint(f);
  u += 0x7FFFu + ((u >> 16) & 1u);   // RNE
  return (unsigned short)(u >> 16);
}

// ---- merged pack: A = [x|h] -> bf16 row-major (B_DIM,K_DIM);
//      B = 8 weight mats -> bf16 (N_DIM,K_DIM), gate-interleaved rows ----
__global__ void pack_AB_kernel(const float* __restrict__ x, const float* __restrict__ h,
                               const float* __restrict__ Wxi, const float* __restrict__ Whi,
                               const float* __restrict__ Wxf, const float* __restrict__ Whf,
                               const float* __restrict__ Wxc, const float* __restrict__ Whc,
                               const float* __restrict__ Wxo, const float* __restrict__ Who,
                               unsigned short* __restrict__ outA,
                               unsigned short* __restrict__ outB) {
  const int totalA = B_DIM * K_DIM / 8;             // 2M 16B-units
  const int total  = totalA + N_DIM * K_DIM / 8;    // +1M
  for (int idx = blockIdx.x * blockDim.x + threadIdx.x; idx < total;
       idx += gridDim.x * blockDim.x) {
    const float* src;
    unsigned short* dst;
    if (idx < totalA) {
      int row = idx >> 8;              // K_DIM/8 = 256 units/row
      int col = (idx & 255) * 8;
      src = (col < I_DIM) ? (x + (size_t)row * I_DIM + col)
                          : (h + (size_t)row * H_DIM + (col - I_DIM));
      dst = outA + (size_t)idx * 8;
    } else {
      int u2 = idx - totalA;
      int r = u2 >> 8;
      int k = (u2 & 255) * 8;
      int g = (r >> 4) & 3;
      int hh = ((r >> 6) << 4) | (r & 15);
      src = (k < I_DIM)
          ? ((g == 0 ? Wxi : g == 1 ? Wxf : g == 2 ? Wxc : Wxo) + (size_t)hh * I_DIM + k)
          : ((g == 0 ? Whi : g == 1 ? Whf : g == 2 ? Whc : Who) + (size_t)hh * H_DIM + (k - I_DIM));
      dst = outB + (size_t)u2 * 8;
    }
    const float4* s4 = (const float4*)src;
    float4 v0 = s4[0], v1 = s4[1];
    bf16x8 o;
    o[0] = f2bf(v0.x); o[1] = f2bf(v0.y); o[2] = f2bf(v0.z); o[3] = f2bf(v0.w);
    o[4] = f2bf(v1.x); o[5] = f2bf(v1.y); o[6] = f2bf(v1.z); o[7] = f2bf(v1.w);
    *(bf16x8*)dst = o;
  }
}

// ---- GEMM 256x256 tile, BK=64, 8 waves (2Mx4N) ----
// LDS map (bytes): sA[buf][half] = buf*32768 + half*16384            (0..65536)
//                  sB[buf][half] = 65536 + buf*32768 + half*16384    (65536..131072)

#define STAGE(gptr, slotoff, ktile) do {                                          \
    int _ktc = (ktile) < NKT ? (ktile) : (NKT - 1);                               \
    const unsigned short* _g = (gptr) + (size_t)_ktc * 64;                        \
    __builtin_amdgcn_global_load_lds(                                             \
        (const __attribute__((address_space(1))) void*)_g,                        \
        (__attribute__((address_space(3))) void*)(lds + (slotoff) + wid * 1024),  \
        16, 0, 0);                                                                \
    __builtin_amdgcn_global_load_lds(                                             \
        (const __attribute__((address_space(1))) void*)(_g + (size_t)64 * K_DIM), \
        (__attribute__((address_space(3))) void*)(lds + (slotoff) + 8192 + wid * 1024), \
        16, 0, 0);                                                                \
  } while (0)

// phase (MH, kk): 16 independent MFMAs, acc rows MH*4..MH*4+3, one kk slice
#define MFMAP(MH, AR, BR)                                                         \
  _Pragma("unroll") for (int mf = 0; mf < 4; ++mf)                                \
  _Pragma("unroll") for (int nn = 0; nn < 4; ++nn)                                \
    acc[(MH)*4 + mf][nn] = __builtin_amdgcn_mfma_f32_16x16x32_bf16(               \
        AR[mf], BR[nn], acc[(MH)*4 + mf][nn], 0, 0, 0)

#define RD_AQ(DST, MH, KOFF, BO)                                                  \
  _Pragma("unroll") for (int mf = 0; mf < 4; ++mf)                                \
    DST[mf] = *(const bf16x8*)(ldsAr + (BO) + (MH)*8192 + mf * 2048 + (KOFF));

#define RD_BH(DST, KOFF, BO)                                                      \
  _Pragma("unroll") for (int nn = 0; nn < 4; ++nn)                                \
    DST[nn] = *(const bf16x8*)(ldsBr + (BO) + nn * 2048 + (KOFF));

#define KTILE(BUF, KT) do {                                                       \
    const int _bo = (BUF) * 32768;                                                \
    const int _bo1 = ((BUF) ^ 1) * 32768;                                         \
    /* p0 (free-run, no trailing barrier) */                                      \
    __builtin_amdgcn_s_setprio(1);                                                \
    MFMAP(0, AQa, BHa);                                                           \
    __builtin_amdgcn_s_setprio(0);                                                \
    RD_AQ(AQb, 1, rd0, _bo);                                                      \
    /* p1 */                                                                      \
    __builtin_amdgcn_s_setprio(1);                                                \
    MFMAP(1, AQb, BHa);                                                           \
    __builtin_amdgcn_s_setprio(0);                                                \
    RD_BH(BHb, rd1, _bo);                                                         \
    RD_AQ(AQa, 0, rd1, _bo);                                                      \
    __builtin_amdgcn_s_barrier();   /* LOAD-BEARING: B-slots of buf[T] fully */   \
    /* p2: stage B(T+2) into buf[T]   read after this point                 */    \
    __builtin_amdgcn_s_setprio(1);                                                \
    MFMAP(0, AQa, BHb);                                                           \
    __builtin_amdgcn_s_setprio(0);                                                \
    RD_AQ(AQb, 1, rd1, _bo);                                                      \
    STAGE(gB0p, 65536 + _bo, (KT) + 2);                                           \
    STAGE(gB1p, 65536 + _bo + 16384, (KT) + 2);                                   \
    asm volatile("s_waitcnt vmcnt(4)" ::: "memory");                              \
    __builtin_amdgcn_s_barrier();   /* LOAD-BEARING: makes vmcnt collective */    \
    /* p3 (free-run, no trailing barrier): cross-buffer reads of T+1 */           \
    __builtin_amdgcn_s_setprio(1);                                                \
    MFMAP(1, AQb, BHb);                                                           \
    __builtin_amdgcn_s_setprio(0);                                                \
    RD_AQ(AQa, 0, rd0, _bo1);                                                     \
    RD_BH(BHa, rd0, _bo1);                                                        \
    STAGE(gA0p, _bo, (KT) + 2);                                                   \
    STAGE(gA1p, _bo + 16384, (KT) + 2);                                           \
  } while (0)

__launch_bounds__(512, 2)
__global__ void lstm_gemm_kernel(const unsigned short* __restrict__ A,
                                 const unsigned short* __restrict__ Bp,
                                 const float* __restrict__ c_prev,
                                 const float* __restrict__ bxi, const float* __restrict__ bhi,
                                 const float* __restrict__ bxf, const float* __restrict__ bhf,
                                 const float* __restrict__ bxc, const float* __restrict__ bhc,
                                 const float* __restrict__ bxo, const float* __restrict__ bho,
                                 float* __restrict__ out) {
  __shared__ __align__(16) char lds[131072];

  // XCD-aware bijective swizzle (512 % 8 == 0)
  const int nwg = gridDim.x;
  int bid = blockIdx.x;
  int q = nwg >> 3;
  int wg = (bid & 7) * q + (bid >> 3);
  int bm = wg >> 4;          // 32 M-tiles
  int bn = wg & 15;          // 16 N-tiles

  int tid = threadIdx.x;
  int lane = tid & 63;
  int wid = tid >> 6;        // 8 waves
  int wm = wid >> 2;         // 2 M-wave rows (128 rows each)
  int wn = wid & 3;          // 4 N-wave cols (64 cols each)

  // staging addresses: per half-tile, wave covers 8 rows x 128B; pre-swizzled
  // global source (rule #21): linear LDS dest, src chunk XOR row&7, same XOR on read.
  int srow = lane >> 3;                 // row within 8-row stripe
  int schunk = (lane & 7) ^ srow;       // swizzled 16B chunk
  const unsigned short* gA0p = A  + (size_t)(bm * 256 + wid * 8 + srow) * K_DIM + schunk * 8;
  const unsigned short* gA1p = gA0p + (size_t)128 * K_DIM;
  const unsigned short* gB0p = Bp + (size_t)(bn * 256 + wid * 8 + srow) * K_DIM + schunk * 8;
  const unsigned short* gB1p = gB0p + (size_t)128 * K_DIM;

  // LDS read bases (byte ptrs); frag row&7 == lane&7 for all fragment rows.
  int c15 = lane & 15;
  int kl = lane >> 4;                   // k-group 0..3
  const char* ldsAr = lds + wm * 16384 + c15 * 128;
  const char* ldsBr = lds + 65536 + (wn >> 1) * 16384 + ((wn & 1) * 64 + c15) * 128;
  int rd0 = ((kl) ^ (lane & 7)) << 4;         // kk=0 chunk
  int rd1 = ((4 | kl) ^ (lane & 7)) << 4;     // kk=1 chunk

  f32x4 acc[8][4];
  f32x4 zero = {0.f, 0.f, 0.f, 0.f};
#pragma unroll
  for (int m = 0; m < 8; ++m)
#pragma unroll
    for (int n = 0; n < 4; ++n) acc[m][n] = zero;

  bf16x8 AQa[4], AQb[4];   // A-quarter ping/pong (4 m-frags x 1 kk each)
  bf16x8 BHa[4], BHb[4];   // B kk-half ping/pong (4 n-frags each)

  // ---- prologue: stage tile0 -> buf0, tile1 -> buf1 (16 loads);
  // vmcnt(8) -> buf0 landed collectively after barrier; pre-read p0 operands. ----
  STAGE(gA0p, 0, 0);
  STAGE(gA1p, 16384, 0);
  STAGE(gB0p, 65536, 0);
  STAGE(gB1p, 65536 + 16384, 0);
  STAGE(gA0p, 32768, 1);
  STAGE(gA1p, 32768 + 16384, 1);
  STAGE(gB0p, 65536 + 32768, 1);
  STAGE(gB1p, 65536 + 32768 + 16384, 1);
  asm volatile("s_waitcnt vmcnt(8)" ::: "memory");
  __builtin_amdgcn_s_barrier();
  RD_AQ(AQa, 0, rd0, 0);
  RD_BH(BHa, rd0, 0);

#pragma unroll 1
  for (int kt = 0; kt < NKT; kt += 2) {
    KTILE(0, kt);
    KTILE(1, kt + 1);
  }

  // ---- fused LSTM epilogue: lane owns hidden unit h; acc[mi][g][j] = gate g ----
  int h = (bn * 4 + wn) * 16 + c15;
  float bi = bxi[h] + bhi[h];
  float bf_ = bxf[h] + bhf[h];
  float bc = bxc[h] + bhc[h];
  float bo = bxo[h] + bho[h];
  int row0 = bm * 256 + wm * 128 + kl * 4;
#pragma unroll
  for (int mi = 0; mi < 8; ++mi) {
#pragma unroll
    for (int j = 0; j < 4; ++j) {
      int r = row0 + mi * 16 + j;
      size_t off = (size_t)r * H_DIM + h;
      float zi = acc[mi][0][j] + bi;
      float zf = acc[mi][1][j] + bf_;
      float zc = acc[mi][2][j] + bc;
      float zo = acc[mi][3][j] + bo;
      float ig = 1.f / (1.f + __expf(-zi));
      float fg = 1.f / (1.f + __expf(-zf));
      float e2 = __expf(-2.f * zc);
      float gg = (1.f - e2) / (1.f + e2);       // tanh(zc)
      float og = 1.f / (1.f + __expf(-zo));
      float cp = c_prev[off];
      float cn = fg * cp + ig * gg;
      float e2c = __expf(-2.f * cn);
      float th = (1.f - e2c) / (1.f + e2c);     // tanh(cn)
      out[off] = og * th;                        // h_new
      out[(size_t)B_DIM * H_DIM + off] = cn;     // c_new
    }
  }
}

extern "C" void kernel_launch(void* const* d_in, const int* in_sizes, int n_in,
                              void* d_out, int out_size, void* d_ws, size_t ws_size,
                              hipStream_t stream) {
  const float* x      = (const float*)d_in[0];
  const float* h_prev = (const float*)d_in[1];
  const float* c_prev = (const float*)d_in[2];
  const float* Wxi = (const float*)d_in[3];
  const float* Whi = (const float*)d_in[4];
  const float* Wxf = (const float*)d_in[5];
  const float* Whf = (const float*)d_in[6];
  const float* Wxc = (const float*)d_in[7];
  const float* Whc = (const float*)d_in[8];
  const float* Wxo = (const float*)d_in[9];
  const float* Who = (const float*)d_in[10];
  const float* bxi = (const float*)d_in[11];
  const float* bhi = (const float*)d_in[12];
  const float* bxf = (const float*)d_in[13];
  const float* bhf = (const float*)d_in[14];
  const float* bxc = (const float*)d_in[15];
  const float* bhc = (const float*)d_in[16];
  const float* bxo = (const float*)d_in[17];
  const float* bho = (const float*)d_in[18];

  unsigned short* Abf = (unsigned short*)d_ws;                                      // 32 MiB
  unsigned short* Bbf = (unsigned short*)((char*)d_ws + (size_t)B_DIM * K_DIM * 2); // +16 MiB

  pack_AB_kernel<<<2048, 256, 0, stream>>>(x, h_prev,
      Wxi, Whi, Wxf, Whf, Wxc, Whc, Wxo, Who, Abf, Bbf);
  lstm_gemm_kernel<<<512, 512, 0, stream>>>(Abf, Bbf, c_prev,
      bxi, bhi, bxf, bhf, bxc, bhc, bxo, bho, (float*)d_out);
}